// Round 4
// baseline (356.061 us; speedup 1.0000x reference)
//
#include <hip/hip_runtime.h>

typedef unsigned short u16;
typedef __attribute__((ext_vector_type(8))) __bf16 bf16x8;
typedef __attribute__((ext_vector_type(4))) float f32x4;

#define MFMA16(a, b, c) __builtin_amdgcn_mfma_f32_16x16x32_bf16((a), (b), (c), 0, 0, 0)

__device__ __forceinline__ u16 f2bf(float f) {
  union { float f; unsigned u; } c; c.f = f;
  unsigned u = c.u;
  u += 0x7FFFu + ((u >> 16) & 1u);   // round-to-nearest-even
  return (u16)(u >> 16);
}

__device__ __forceinline__ bf16x8 pack8(const float4& a, const float4& b) {
  union { u16 u[8]; bf16x8 v; } r;
  r.u[0] = f2bf(a.x); r.u[1] = f2bf(a.y); r.u[2] = f2bf(a.z); r.u[3] = f2bf(a.w);
  r.u[4] = f2bf(b.x); r.u[5] = f2bf(b.y); r.u[6] = f2bf(b.z); r.u[7] = f2bf(b.w);
  return r.v;
}

// ---------------------------------------------------------------------------
// fp32 src slice (1024 x 1024 starting at column col0, row stride C_ld)
//   -> bf16 dst (1024 x 1024) transposed.
// ---------------------------------------------------------------------------
__global__ __launch_bounds__(256) void transpose_cvt_k(const float* __restrict__ src,
                                                       u16* __restrict__ dst,
                                                       int C_ld, int col0) {
  __shared__ u16 t[32][33];
  const int bx = blockIdx.x * 32;
  const int by = blockIdx.y * 32;
  const int tx = threadIdx.x;
  for (int yo = threadIdx.y; yo < 32; yo += 8)
    t[yo][tx] = f2bf(src[(size_t)(by + yo) * C_ld + col0 + bx + tx]);
  __syncthreads();
  for (int yo = threadIdx.y; yo < 32; yo += 8)
    dst[(size_t)(bx + yo) * 1024 + by + tx] = t[tx][yo];
}

// ---------------------------------------------------------------------------
// T5 bias table: tab[delta + 2047][h], delta = j - i. fp32, as-shown semantics:
// bucket = 8 + trunc(2*log2(n/8)) capped 15 (n=64 -> 6 -> 14).
// ---------------------------------------------------------------------------
__global__ void bias_table_k(const float* __restrict__ rel_emb, float* __restrict__ tab) {
  int idx = blockIdx.x * blockDim.x + threadIdx.x;
  if (idx >= 4095) return;
  int delta = idx - 2047;   // j - i
  int n = -delta;           // i - j
  int ret = 0;
  if (n < 0) { ret = 16; n = -n; }
  int bucket;
  if (n < 8) {
    bucket = n;
  } else {
    int vl = 8 + (int)(2.0f * __log2f((float)n * 0.125f));
    bucket = vl < 15 ? vl : 15;
  }
  bucket += ret;
#pragma unroll
  for (int h = 0; h < 16; h++)
    tab[(size_t)idx * 16 + h] = rel_emb[bucket * 16 + h];
}

// ---------------------------------------------------------------------------
// Projection GEMM: Xf(4096x1024 fp32) @ WT^T (WT: 1024x1024 bf16 [out][in]).
// mode: 0 -> Q[b][h][n][d], 1 -> K[b][h][n][d], 2 -> VT[b][h][d][n].
// ---------------------------------------------------------------------------
__global__ __launch_bounds__(256) void proj_gemm_k(
    const float* __restrict__ Xf, const u16* __restrict__ WT, int mode,
    u16* __restrict__ dstQ, u16* __restrict__ dstK, u16* __restrict__ dstVT) {
  __shared__ __align__(16) u16 As[128 * 32];
  __shared__ __align__(16) u16 Bs[128 * 32];
  f32x4 acc[4][4];
#pragma unroll
  for (int i = 0; i < 4; i++)
#pragma unroll
    for (int j = 0; j < 4; j++) acc[i][j] = f32x4{0.f, 0.f, 0.f, 0.f};

  const int m0 = blockIdx.x * 128;
  const int n0 = blockIdx.y * 128;
  const int tid  = threadIdx.x;
  const int lane = tid & 63;
  const int wave = tid >> 6;
  const int wr = (wave >> 1) * 64;
  const int wc = (wave & 1) * 64;
  const int lr = lane & 15;
  const int lk = (lane >> 4) * 8;
  const int r0 = tid >> 2;
  const int sg = (tid & 3) * 8;

  const float* ap0 = Xf + (size_t)(m0 + r0) * 1024 + sg;
  const float* ap1 = Xf + (size_t)(m0 + 64 + r0) * 1024 + sg;
  const u16* bp0 = WT + (size_t)(n0 + r0) * 1024 + sg;
  const u16* bp1 = WT + (size_t)(n0 + 64 + r0) * 1024 + sg;
  u16* as0 = As + r0 * 32 + sg;
  u16* as1 = As + (64 + r0) * 32 + sg;
  u16* bs0 = Bs + r0 * 32 + sg;
  u16* bs1 = Bs + (64 + r0) * 32 + sg;

  for (int k0 = 0; k0 < 1024; k0 += 32) {
    __syncthreads();
    float4 a00 = *(const float4*)(ap0 + k0);
    float4 a01 = *(const float4*)(ap0 + k0 + 4);
    float4 a10 = *(const float4*)(ap1 + k0);
    float4 a11 = *(const float4*)(ap1 + k0 + 4);
    bf16x8 vb0 = *(const bf16x8*)(bp0 + k0);
    bf16x8 vb1 = *(const bf16x8*)(bp1 + k0);
    *(bf16x8*)as0 = pack8(a00, a01);
    *(bf16x8*)as1 = pack8(a10, a11);
    *(bf16x8*)bs0 = vb0;
    *(bf16x8*)bs1 = vb1;
    __syncthreads();
    bf16x8 af[4], bfv[4];
#pragma unroll
    for (int i = 0; i < 4; i++)
      af[i] = *(const bf16x8*)(As + (wr + i * 16 + lr) * 32 + lk);
#pragma unroll
    for (int j = 0; j < 4; j++)
      bfv[j] = *(const bf16x8*)(Bs + (wc + j * 16 + lr) * 32 + lk);
#pragma unroll
    for (int i = 0; i < 4; i++)
#pragma unroll
      for (int j = 0; j < 4; j++)
        acc[i][j] = MFMA16(af[i], bfv[j], acc[i][j]);
  }

  const int orow = (lane >> 4) * 4, ocol = lane & 15;
#pragma unroll
  for (int i = 0; i < 4; i++)
#pragma unroll
    for (int j = 0; j < 4; j++)
#pragma unroll
      for (int r = 0; r < 4; r++) {
        int grow = m0 + wr + i * 16 + orow + r;   // token
        int gcol = n0 + wc + j * 16 + ocol;       // channel
        int b = grow >> 11, n = grow & 2047;
        int h = gcol >> 6, d = gcol & 63;
        u16 bv = f2bf(acc[i][j][r]);
        if (mode == 0)
          dstQ[(((size_t)b * 16 + h) * 2048 + n) * 64 + d] = bv;
        else if (mode == 1)
          dstK[(((size_t)b * 16 + h) * 2048 + n) * 64 + d] = bv;
        else
          dstVT[(((size_t)b * 16 + h) * 64 + d) * 2048 + n] = bv;
      }
}

// ---------------------------------------------------------------------------
// Flash attention with T5 bias. Block = 64 Q-rows of one (b,h); K-chunks of 64.
// ---------------------------------------------------------------------------
__global__ __launch_bounds__(256) void attn_k(
    const u16* __restrict__ Q, const u16* __restrict__ Kb,
    const u16* __restrict__ VT, const float* __restrict__ bias_tab,
    u16* __restrict__ AO) {
  const int tid = threadIdx.x;
  const int lane = tid & 63, wave = tid >> 6;
  const int lr = lane & 15, lq = lane >> 4, lk = lq * 8;
  const int bh = blockIdx.y, b = bh >> 4, h = bh & 15;
  const int q0 = blockIdx.x * 64;

  __shared__ __align__(16) u16 Qs[64 * 72];
  __shared__ __align__(16) u16 Ks[64 * 72];
  __shared__ __align__(16) u16 Vs[64 * 72];
  __shared__ __align__(16) u16 Ps[64 * 72];
  __shared__ float Bls[128];

  const u16* Qg = Q + ((size_t)bh * 2048 + q0) * 64;
  {
    int ra = tid >> 3, sa = (tid & 7) * 8;
    *(bf16x8*)(Qs + ra * 72 + sa)        = *(const bf16x8*)(Qg + (size_t)ra * 64 + sa);
    *(bf16x8*)(Qs + (32 + ra) * 72 + sa) = *(const bf16x8*)(Qg + (size_t)(32 + ra) * 64 + sa);
  }
  __syncthreads();
  bf16x8 qf0 = *(const bf16x8*)(Qs + (wave * 16 + lr) * 72 + lk);
  bf16x8 qf1 = *(const bf16x8*)(Qs + (wave * 16 + lr) * 72 + 32 + lk);

  float m_run[4], l_run[4];
  f32x4 o[4];
#pragma unroll
  for (int r = 0; r < 4; r++) { m_run[r] = -1.0e30f; l_run[r] = 0.f; }
#pragma unroll
  for (int dt = 0; dt < 4; dt++) o[dt] = f32x4{0.f, 0.f, 0.f, 0.f};

  const u16* Kg = Kb + (size_t)bh * 2048 * 64;
  const u16* Vg = VT + (size_t)bh * 64 * 2048;
  const int i_base = wave * 16 + lq * 4;
  const float scale = 0.125f;

  for (int kc = 0; kc < 2048; kc += 64) {
    __syncthreads();
    {
      int ra = tid >> 3, sa = (tid & 7) * 8;
      *(bf16x8*)(Ks + ra * 72 + sa)        = *(const bf16x8*)(Kg + (size_t)(kc + ra) * 64 + sa);
      *(bf16x8*)(Ks + (32 + ra) * 72 + sa) = *(const bf16x8*)(Kg + (size_t)(kc + 32 + ra) * 64 + sa);
      *(bf16x8*)(Vs + ra * 72 + sa)        = *(const bf16x8*)(Vg + (size_t)ra * 2048 + kc + sa);
      *(bf16x8*)(Vs + (32 + ra) * 72 + sa) = *(const bf16x8*)(Vg + (size_t)(32 + ra) * 2048 + kc + sa);
      if (tid < 127) Bls[tid] = bias_tab[(size_t)(kc - q0 + tid - 63 + 2047) * 16 + h];
    }
    __syncthreads();

    f32x4 sc[4];
#pragma unroll
    for (int jt = 0; jt < 4; jt++) {
      bf16x8 kb0 = *(const bf16x8*)(Ks + (jt * 16 + lr) * 72 + lk);
      bf16x8 kb1 = *(const bf16x8*)(Ks + (jt * 16 + lr) * 72 + 32 + lk);
      f32x4 z = {0.f, 0.f, 0.f, 0.f};
      z = MFMA16(qf0, kb0, z);
      z = MFMA16(qf1, kb1, z);
      sc[jt] = z;
    }

    float mc[4] = {-1.0e30f, -1.0e30f, -1.0e30f, -1.0e30f};
#pragma unroll
    for (int jt = 0; jt < 4; jt++) {
      int base = jt * 16 + lr - i_base + 63;
#pragma unroll
      for (int r = 0; r < 4; r++) {
        float sv = sc[jt][r] * scale + Bls[base - r];
        sc[jt][r] = sv;
        mc[r] = fmaxf(mc[r], sv);
      }
    }
#pragma unroll
    for (int m = 1; m < 16; m <<= 1)
#pragma unroll
      for (int r = 0; r < 4; r++)
        mc[r] = fmaxf(mc[r], __shfl_xor(mc[r], m));

    float alpha[4], ls[4];
#pragma unroll
    for (int r = 0; r < 4; r++) {
      float mn = fmaxf(m_run[r], mc[r]);
      alpha[r] = __expf(m_run[r] - mn);
      m_run[r] = mn;
      ls[r] = 0.f;
    }
#pragma unroll
    for (int jt = 0; jt < 4; jt++)
#pragma unroll
      for (int r = 0; r < 4; r++) {
        float p = __expf(sc[jt][r] - m_run[r]);
        sc[jt][r] = p;
        ls[r] += p;
      }
#pragma unroll
    for (int m = 1; m < 16; m <<= 1)
#pragma unroll
      for (int r = 0; r < 4; r++)
        ls[r] += __shfl_xor(ls[r], m);
#pragma unroll
    for (int r = 0; r < 4; r++)
      l_run[r] = l_run[r] * alpha[r] + ls[r];
#pragma unroll
    for (int dt = 0; dt < 4; dt++)
#pragma unroll
      for (int r = 0; r < 4; r++)
        o[dt][r] *= alpha[r];

#pragma unroll
    for (int jt = 0; jt < 4; jt++)
#pragma unroll
      for (int r = 0; r < 4; r++)
        Ps[(wave * 16 + lq * 4 + r) * 72 + jt * 16 + lr] = f2bf(sc[jt][r]);
    __syncthreads();

    bf16x8 p0 = *(const bf16x8*)(Ps + (wave * 16 + lr) * 72 + lk);
    bf16x8 p1 = *(const bf16x8*)(Ps + (wave * 16 + lr) * 72 + 32 + lk);
#pragma unroll
    for (int dt = 0; dt < 4; dt++) {
      bf16x8 v0 = *(const bf16x8*)(Vs + (dt * 16 + lr) * 72 + lk);
      bf16x8 v1 = *(const bf16x8*)(Vs + (dt * 16 + lr) * 72 + 32 + lk);
      o[dt] = MFMA16(p0, v0, o[dt]);
      o[dt] = MFMA16(p1, v1, o[dt]);
    }
  }

#pragma unroll
  for (int dt = 0; dt < 4; dt++)
#pragma unroll
    for (int r = 0; r < 4; r++) {
      float ov = o[dt][r] / l_run[r];
      int n = q0 + wave * 16 + lq * 4 + r;
      int d = dt * 16 + lr;
      AO[((size_t)b * 2048 + n) * 1024 + h * 64 + d] = f2bf(ov);
    }
}

// ---------------------------------------------------------------------------
// Output GEMM: AO(4096x1024 bf16) @ WoT^T + bo -> out  *** FLOAT32 OUT ***
// ---------------------------------------------------------------------------
__global__ __launch_bounds__(256) void out_gemm_k(
    const u16* __restrict__ AO, const u16* __restrict__ WoT,
    const float* __restrict__ bo, float* __restrict__ out) {
  __shared__ __align__(16) u16 As[128 * 32];
  __shared__ __align__(16) u16 Bs[128 * 32];
  f32x4 acc[4][4];
#pragma unroll
  for (int i = 0; i < 4; i++)
#pragma unroll
    for (int j = 0; j < 4; j++) acc[i][j] = f32x4{0.f, 0.f, 0.f, 0.f};

  const int m0 = blockIdx.x * 128;
  const int n0 = blockIdx.y * 128;
  const int tid  = threadIdx.x;
  const int lane = tid & 63;
  const int wave = tid >> 6;
  const int wr = (wave >> 1) * 64;
  const int wc = (wave & 1) * 64;
  const int lr = lane & 15;
  const int lk = (lane >> 4) * 8;
  const int r0 = tid >> 2;
  const int sg = (tid & 3) * 8;

  const u16* ap0 = AO + (size_t)(m0 + r0) * 1024 + sg;
  const u16* ap1 = AO + (size_t)(m0 + 64 + r0) * 1024 + sg;
  const u16* bp0 = WoT + (size_t)(n0 + r0) * 1024 + sg;
  const u16* bp1 = WoT + (size_t)(n0 + 64 + r0) * 1024 + sg;
  u16* as0 = As + r0 * 32 + sg;
  u16* as1 = As + (64 + r0) * 32 + sg;
  u16* bs0 = Bs + r0 * 32 + sg;
  u16* bs1 = Bs + (64 + r0) * 32 + sg;

  for (int k0 = 0; k0 < 1024; k0 += 32) {
    __syncthreads();
    bf16x8 va0 = *(const bf16x8*)(ap0 + k0);
    bf16x8 va1 = *(const bf16x8*)(ap1 + k0);
    bf16x8 vb0 = *(const bf16x8*)(bp0 + k0);
    bf16x8 vb1 = *(const bf16x8*)(bp1 + k0);
    *(bf16x8*)as0 = va0;
    *(bf16x8*)as1 = va1;
    *(bf16x8*)bs0 = vb0;
    *(bf16x8*)bs1 = vb1;
    __syncthreads();
    bf16x8 af[4], bfv[4];
#pragma unroll
    for (int i = 0; i < 4; i++)
      af[i] = *(const bf16x8*)(As + (wr + i * 16 + lr) * 32 + lk);
#pragma unroll
    for (int j = 0; j < 4; j++)
      bfv[j] = *(const bf16x8*)(Bs + (wc + j * 16 + lr) * 32 + lk);
#pragma unroll
    for (int i = 0; i < 4; i++)
#pragma unroll
      for (int j = 0; j < 4; j++)
        acc[i][j] = MFMA16(af[i], bfv[j], acc[i][j]);
  }

  const int orow = (lane >> 4) * 4, ocol = lane & 15;
#pragma unroll
  for (int i = 0; i < 4; i++)
#pragma unroll
    for (int j = 0; j < 4; j++) {
      int gcol = n0 + wc + j * 16 + ocol;
      float bof = bo[gcol];
#pragma unroll
      for (int r = 0; r < 4; r++) {
        int grow = m0 + wr + i * 16 + orow + r;
        out[(size_t)grow * 1024 + gcol] = acc[i][j][r] + bof;   // fp32 store
      }
    }
}

// ---------------------------------------------------------------------------
extern "C" void kernel_launch(void* const* d_in, const int* in_sizes, int n_in,
                              void* d_out, int out_size, void* d_ws, size_t ws_size,
                              hipStream_t stream) {
  const float* x    = (const float*)d_in[0];
  const float* Wq   = (const float*)d_in[1];
  const float* Wkv  = (const float*)d_in[2];
  const float* Wo   = (const float*)d_in[3];
  const float* bo   = (const float*)d_in[4];
  const float* rel  = (const float*)d_in[5];
  float* out = (float*)d_out;                 // *** fp32 output ***

  char* ws = (char*)d_ws;
  u16*   Wbuf = (u16*)(ws + 0);          //  2 MB (reused 3x)
  u16*   WoT  = (u16*)(ws + 2097152);    //  2 MB
  float* btab = (float*)(ws + 4194304);  //  0.25 MB
  u16*   Qb   = (u16*)(ws + 4456448);    //  8 MB
  u16*   Kbuf = (u16*)(ws + 12845056);   //  8 MB
  u16*   VTb  = (u16*)(ws + 21233664);   //  8 MB
  u16*   AO   = (u16*)(ws + 29622272);   //  8 MB

  bias_table_k<<<16, 256, 0, stream>>>(rel, btab);
  transpose_cvt_k<<<dim3(32, 32), dim3(32, 8), 0, stream>>>(Wo, WoT, 1024, 0);

  transpose_cvt_k<<<dim3(32, 32), dim3(32, 8), 0, stream>>>(Wq, Wbuf, 1024, 0);
  proj_gemm_k<<<dim3(32, 8), 256, 0, stream>>>(x, Wbuf, 0, Qb, Kbuf, VTb);
  transpose_cvt_k<<<dim3(32, 32), dim3(32, 8), 0, stream>>>(Wkv, Wbuf, 2048, 0);
  proj_gemm_k<<<dim3(32, 8), 256, 0, stream>>>(x, Wbuf, 1, Qb, Kbuf, VTb);
  transpose_cvt_k<<<dim3(32, 32), dim3(32, 8), 0, stream>>>(Wkv, Wbuf, 2048, 1024);
  proj_gemm_k<<<dim3(32, 8), 256, 0, stream>>>(x, Wbuf, 2, Qb, Kbuf, VTb);

  attn_k<<<dim3(32, 32), 256, 0, stream>>>(Qb, Kbuf, VTb, btab, AO);
  out_gemm_k<<<dim3(32, 8), 256, 0, stream>>>(AO, WoT, bo, out);
}

// Round 5
// 321.193 us; speedup vs baseline: 1.1086x; 1.1086x over previous
//
#include <hip/hip_runtime.h>

typedef unsigned short u16;
typedef __attribute__((ext_vector_type(8))) __bf16 bf16x8;
typedef __attribute__((ext_vector_type(4))) float f32x4;

#define MFMA16(a, b, c) __builtin_amdgcn_mfma_f32_16x16x32_bf16((a), (b), (c), 0, 0, 0)

__device__ __forceinline__ u16 f2bf(float f) {
  union { float f; unsigned u; } c; c.f = f;
  unsigned u = c.u;
  u += 0x7FFFu + ((u >> 16) & 1u);   // round-to-nearest-even
  return (u16)(u >> 16);
}

__device__ __forceinline__ bf16x8 pack8(const float4& a, const float4& b) {
  union { u16 u[8]; bf16x8 v; } r;
  r.u[0] = f2bf(a.x); r.u[1] = f2bf(a.y); r.u[2] = f2bf(a.z); r.u[3] = f2bf(a.w);
  r.u[4] = f2bf(b.x); r.u[5] = f2bf(b.y); r.u[6] = f2bf(b.z); r.u[7] = f2bf(b.w);
  return r.v;
}

// ---------------------------------------------------------------------------
// fp32 src slice (1024 x 1024 starting at column col0, row stride C_ld)
//   -> bf16 dst (1024 x 1024) transposed.
// ---------------------------------------------------------------------------
__global__ __launch_bounds__(256) void transpose_cvt_k(const float* __restrict__ src,
                                                       u16* __restrict__ dst,
                                                       int C_ld, int col0) {
  __shared__ u16 t[32][33];
  const int bx = blockIdx.x * 32;
  const int by = blockIdx.y * 32;
  const int tx = threadIdx.x;
  for (int yo = threadIdx.y; yo < 32; yo += 8)
    t[yo][tx] = f2bf(src[(size_t)(by + yo) * C_ld + col0 + bx + tx]);
  __syncthreads();
  for (int yo = threadIdx.y; yo < 32; yo += 8)
    dst[(size_t)(bx + yo) * 1024 + by + tx] = t[tx][yo];
}

// ---------------------------------------------------------------------------
// T5 bias table: tab[delta + 2047][h], delta = j - i. fp32, as-shown semantics.
// ---------------------------------------------------------------------------
__global__ void bias_table_k(const float* __restrict__ rel_emb, float* __restrict__ tab) {
  int idx = blockIdx.x * blockDim.x + threadIdx.x;
  if (idx >= 4095) return;
  int delta = idx - 2047;   // j - i
  int n = -delta;           // i - j
  int ret = 0;
  if (n < 0) { ret = 16; n = -n; }
  int bucket;
  if (n < 8) {
    bucket = n;
  } else {
    int vl = 8 + (int)(2.0f * __log2f((float)n * 0.125f));
    bucket = vl < 15 ? vl : 15;
  }
  bucket += ret;
#pragma unroll
  for (int h = 0; h < 16; h++)
    tab[(size_t)idx * 16 + h] = rel_emb[bucket * 16 + h];
}

// ---------------------------------------------------------------------------
// Fused projection GEMM: Xf(4096x1024 fp32) @ Wall^T (Wall: 3072x1024 bf16
// [out][in]; rows 0-1023 = Q channels, 1024-2047 = K, 2048-3071 = V).
// Grid (32, 24) = 768 blocks (3/CU co-resident). Per-output math identical
// to the verified per-mode kernel (same K-loop, same MFMA order).
// ---------------------------------------------------------------------------
__global__ __launch_bounds__(256) void proj_gemm_k(
    const float* __restrict__ Xf, const u16* __restrict__ WT,
    u16* __restrict__ dstQ, u16* __restrict__ dstK, u16* __restrict__ dstVT) {
  __shared__ __align__(16) u16 As[128 * 32];
  __shared__ __align__(16) u16 Bs[128 * 32];
  f32x4 acc[4][4];
#pragma unroll
  for (int i = 0; i < 4; i++)
#pragma unroll
    for (int j = 0; j < 4; j++) acc[i][j] = f32x4{0.f, 0.f, 0.f, 0.f};

  const int m0 = blockIdx.x * 128;
  const int n0 = blockIdx.y * 128;          // 0..2944 over the 3072 fused cols
  const int tid  = threadIdx.x;
  const int lane = tid & 63;
  const int wave = tid >> 6;
  const int wr = (wave >> 1) * 64;
  const int wc = (wave & 1) * 64;
  const int lr = lane & 15;
  const int lk = (lane >> 4) * 8;
  const int r0 = tid >> 2;
  const int sg = (tid & 3) * 8;

  const float* ap0 = Xf + (size_t)(m0 + r0) * 1024 + sg;
  const float* ap1 = Xf + (size_t)(m0 + 64 + r0) * 1024 + sg;
  const u16* bp0 = WT + (size_t)(n0 + r0) * 1024 + sg;
  const u16* bp1 = WT + (size_t)(n0 + 64 + r0) * 1024 + sg;
  u16* as0 = As + r0 * 32 + sg;
  u16* as1 = As + (64 + r0) * 32 + sg;
  u16* bs0 = Bs + r0 * 32 + sg;
  u16* bs1 = Bs + (64 + r0) * 32 + sg;

  for (int k0 = 0; k0 < 1024; k0 += 32) {
    __syncthreads();
    float4 a00 = *(const float4*)(ap0 + k0);
    float4 a01 = *(const float4*)(ap0 + k0 + 4);
    float4 a10 = *(const float4*)(ap1 + k0);
    float4 a11 = *(const float4*)(ap1 + k0 + 4);
    bf16x8 vb0 = *(const bf16x8*)(bp0 + k0);
    bf16x8 vb1 = *(const bf16x8*)(bp1 + k0);
    *(bf16x8*)as0 = pack8(a00, a01);
    *(bf16x8*)as1 = pack8(a10, a11);
    *(bf16x8*)bs0 = vb0;
    *(bf16x8*)bs1 = vb1;
    __syncthreads();
    bf16x8 af[4], bfv[4];
#pragma unroll
    for (int i = 0; i < 4; i++)
      af[i] = *(const bf16x8*)(As + (wr + i * 16 + lr) * 32 + lk);
#pragma unroll
    for (int j = 0; j < 4; j++)
      bfv[j] = *(const bf16x8*)(Bs + (wc + j * 16 + lr) * 32 + lk);
#pragma unroll
    for (int i = 0; i < 4; i++)
#pragma unroll
      for (int j = 0; j < 4; j++)
        acc[i][j] = MFMA16(af[i], bfv[j], acc[i][j]);
  }

  const int orow = (lane >> 4) * 4, ocol = lane & 15;
#pragma unroll
  for (int i = 0; i < 4; i++)
#pragma unroll
    for (int j = 0; j < 4; j++)
#pragma unroll
      for (int r = 0; r < 4; r++) {
        int grow = m0 + wr + i * 16 + orow + r;   // token
        int gcol = n0 + wc + j * 16 + ocol;       // fused channel 0..3071
        int b = grow >> 11, n = grow & 2047;
        int seg = gcol >> 10;                     // 0=Q, 1=K, 2=V (uniform/block)
        int c = gcol & 1023;
        int h = c >> 6, d = c & 63;
        u16 bv = f2bf(acc[i][j][r]);
        if (seg == 0)
          dstQ[(((size_t)b * 16 + h) * 2048 + n) * 64 + d] = bv;
        else if (seg == 1)
          dstK[(((size_t)b * 16 + h) * 2048 + n) * 64 + d] = bv;
        else
          dstVT[(((size_t)b * 16 + h) * 64 + d) * 2048 + n] = bv;
      }
}

// ---------------------------------------------------------------------------
// Flash attention with T5 bias. Block = 64 Q-rows of one (b,h); K-chunks of 64.
// (Byte-identical to the verified R0/R4 version.)
// ---------------------------------------------------------------------------
__global__ __launch_bounds__(256) void attn_k(
    const u16* __restrict__ Q, const u16* __restrict__ Kb,
    const u16* __restrict__ VT, const float* __restrict__ bias_tab,
    u16* __restrict__ AO) {
  const int tid = threadIdx.x;
  const int lane = tid & 63, wave = tid >> 6;
  const int lr = lane & 15, lq = lane >> 4, lk = lq * 8;
  const int bh = blockIdx.y, b = bh >> 4, h = bh & 15;
  const int q0 = blockIdx.x * 64;

  __shared__ __align__(16) u16 Qs[64 * 72];
  __shared__ __align__(16) u16 Ks[64 * 72];
  __shared__ __align__(16) u16 Vs[64 * 72];
  __shared__ __align__(16) u16 Ps[64 * 72];
  __shared__ float Bls[128];

  const u16* Qg = Q + ((size_t)bh * 2048 + q0) * 64;
  {
    int ra = tid >> 3, sa = (tid & 7) * 8;
    *(bf16x8*)(Qs + ra * 72 + sa)        = *(const bf16x8*)(Qg + (size_t)ra * 64 + sa);
    *(bf16x8*)(Qs + (32 + ra) * 72 + sa) = *(const bf16x8*)(Qg + (size_t)(32 + ra) * 64 + sa);
  }
  __syncthreads();
  bf16x8 qf0 = *(const bf16x8*)(Qs + (wave * 16 + lr) * 72 + lk);
  bf16x8 qf1 = *(const bf16x8*)(Qs + (wave * 16 + lr) * 72 + 32 + lk);

  float m_run[4], l_run[4];
  f32x4 o[4];
#pragma unroll
  for (int r = 0; r < 4; r++) { m_run[r] = -1.0e30f; l_run[r] = 0.f; }
#pragma unroll
  for (int dt = 0; dt < 4; dt++) o[dt] = f32x4{0.f, 0.f, 0.f, 0.f};

  const u16* Kg = Kb + (size_t)bh * 2048 * 64;
  const u16* Vg = VT + (size_t)bh * 64 * 2048;
  const int i_base = wave * 16 + lq * 4;
  const float scale = 0.125f;

  for (int kc = 0; kc < 2048; kc += 64) {
    __syncthreads();
    {
      int ra = tid >> 3, sa = (tid & 7) * 8;
      *(bf16x8*)(Ks + ra * 72 + sa)        = *(const bf16x8*)(Kg + (size_t)(kc + ra) * 64 + sa);
      *(bf16x8*)(Ks + (32 + ra) * 72 + sa) = *(const bf16x8*)(Kg + (size_t)(kc + 32 + ra) * 64 + sa);
      *(bf16x8*)(Vs + ra * 72 + sa)        = *(const bf16x8*)(Vg + (size_t)ra * 2048 + kc + sa);
      *(bf16x8*)(Vs + (32 + ra) * 72 + sa) = *(const bf16x8*)(Vg + (size_t)(32 + ra) * 2048 + kc + sa);
      if (tid < 127) Bls[tid] = bias_tab[(size_t)(kc - q0 + tid - 63 + 2047) * 16 + h];
    }
    __syncthreads();

    f32x4 sc[4];
#pragma unroll
    for (int jt = 0; jt < 4; jt++) {
      bf16x8 kb0 = *(const bf16x8*)(Ks + (jt * 16 + lr) * 72 + lk);
      bf16x8 kb1 = *(const bf16x8*)(Ks + (jt * 16 + lr) * 72 + 32 + lk);
      f32x4 z = {0.f, 0.f, 0.f, 0.f};
      z = MFMA16(qf0, kb0, z);
      z = MFMA16(qf1, kb1, z);
      sc[jt] = z;
    }

    float mc[4] = {-1.0e30f, -1.0e30f, -1.0e30f, -1.0e30f};
#pragma unroll
    for (int jt = 0; jt < 4; jt++) {
      int base = jt * 16 + lr - i_base + 63;
#pragma unroll
      for (int r = 0; r < 4; r++) {
        float sv = sc[jt][r] * scale + Bls[base - r];
        sc[jt][r] = sv;
        mc[r] = fmaxf(mc[r], sv);
      }
    }
#pragma unroll
    for (int m = 1; m < 16; m <<= 1)
#pragma unroll
      for (int r = 0; r < 4; r++)
        mc[r] = fmaxf(mc[r], __shfl_xor(mc[r], m));

    float alpha[4], ls[4];
#pragma unroll
    for (int r = 0; r < 4; r++) {
      float mn = fmaxf(m_run[r], mc[r]);
      alpha[r] = __expf(m_run[r] - mn);
      m_run[r] = mn;
      ls[r] = 0.f;
    }
#pragma unroll
    for (int jt = 0; jt < 4; jt++)
#pragma unroll
      for (int r = 0; r < 4; r++) {
        float p = __expf(sc[jt][r] - m_run[r]);
        sc[jt][r] = p;
        ls[r] += p;
      }
#pragma unroll
    for (int m = 1; m < 16; m <<= 1)
#pragma unroll
      for (int r = 0; r < 4; r++)
        ls[r] += __shfl_xor(ls[r], m);
#pragma unroll
    for (int r = 0; r < 4; r++)
      l_run[r] = l_run[r] * alpha[r] + ls[r];
#pragma unroll
    for (int dt = 0; dt < 4; dt++)
#pragma unroll
      for (int r = 0; r < 4; r++)
        o[dt][r] *= alpha[r];

#pragma unroll
    for (int jt = 0; jt < 4; jt++)
#pragma unroll
      for (int r = 0; r < 4; r++)
        Ps[(wave * 16 + lq * 4 + r) * 72 + jt * 16 + lr] = f2bf(sc[jt][r]);
    __syncthreads();

    bf16x8 p0 = *(const bf16x8*)(Ps + (wave * 16 + lr) * 72 + lk);
    bf16x8 p1 = *(const bf16x8*)(Ps + (wave * 16 + lr) * 72 + 32 + lk);
#pragma unroll
    for (int dt = 0; dt < 4; dt++) {
      bf16x8 v0 = *(const bf16x8*)(Vs + (dt * 16 + lr) * 72 + lk);
      bf16x8 v1 = *(const bf16x8*)(Vs + (dt * 16 + lr) * 72 + 32 + lk);
      o[dt] = MFMA16(p0, v0, o[dt]);
      o[dt] = MFMA16(p1, v1, o[dt]);
    }
  }

#pragma unroll
  for (int dt = 0; dt < 4; dt++)
#pragma unroll
    for (int r = 0; r < 4; r++) {
      float ov = o[dt][r] / l_run[r];
      int n = q0 + wave * 16 + lq * 4 + r;
      int d = dt * 16 + lr;
      AO[((size_t)b * 2048 + n) * 1024 + h * 64 + d] = f2bf(ov);
    }
}

// ---------------------------------------------------------------------------
// Output GEMM: AO(4096x1024 bf16) @ WoT^T + bo -> out (fp32).
// Restructured to 64x128 tiles, grid (64, 8) = 512 blocks (2/CU). Per-output
// K-loop / MFMA order unchanged -> bit-identical results.
// ---------------------------------------------------------------------------
__global__ __launch_bounds__(256) void out_gemm_k(
    const u16* __restrict__ AO, const u16* __restrict__ WoT,
    const float* __restrict__ bo, float* __restrict__ out) {
  __shared__ __align__(16) u16 As[64 * 32];
  __shared__ __align__(16) u16 Bs[128 * 32];
  f32x4 acc[4][2];
#pragma unroll
  for (int i = 0; i < 4; i++)
#pragma unroll
    for (int j = 0; j < 2; j++) acc[i][j] = f32x4{0.f, 0.f, 0.f, 0.f};

  const int m0 = blockIdx.x * 64;
  const int n0 = blockIdx.y * 128;
  const int tid  = threadIdx.x;
  const int lane = tid & 63;
  const int wave = tid >> 6;
  const int wc = wave * 32;            // each wave: 64 rows x 32 cols
  const int lr = lane & 15;
  const int lk = (lane >> 4) * 8;
  const int r0 = tid >> 2;
  const int sg = (tid & 3) * 8;

  const u16* ap  = AO + (size_t)(m0 + r0) * 1024 + sg;
  const u16* bp0 = WoT + (size_t)(n0 + r0) * 1024 + sg;
  const u16* bp1 = WoT + (size_t)(n0 + 64 + r0) * 1024 + sg;
  u16* as  = As + r0 * 32 + sg;
  u16* bs0 = Bs + r0 * 32 + sg;
  u16* bs1 = Bs + (64 + r0) * 32 + sg;

  for (int k0 = 0; k0 < 1024; k0 += 32) {
    __syncthreads();
    bf16x8 va  = *(const bf16x8*)(ap + k0);
    bf16x8 vb0 = *(const bf16x8*)(bp0 + k0);
    bf16x8 vb1 = *(const bf16x8*)(bp1 + k0);
    *(bf16x8*)as  = va;
    *(bf16x8*)bs0 = vb0;
    *(bf16x8*)bs1 = vb1;
    __syncthreads();
    bf16x8 af[4], bfv[2];
#pragma unroll
    for (int i = 0; i < 4; i++)
      af[i] = *(const bf16x8*)(As + (i * 16 + lr) * 32 + lk);
#pragma unroll
    for (int j = 0; j < 2; j++)
      bfv[j] = *(const bf16x8*)(Bs + (wc + j * 16 + lr) * 32 + lk);
#pragma unroll
    for (int i = 0; i < 4; i++)
#pragma unroll
      for (int j = 0; j < 2; j++)
        acc[i][j] = MFMA16(af[i], bfv[j], acc[i][j]);
  }

  const int orow = (lane >> 4) * 4, ocol = lane & 15;
#pragma unroll
  for (int i = 0; i < 4; i++)
#pragma unroll
    for (int j = 0; j < 2; j++) {
      int gcol = n0 + wc + j * 16 + ocol;
      float bof = bo[gcol];
#pragma unroll
      for (int r = 0; r < 4; r++) {
        int grow = m0 + i * 16 + orow + r;
        out[(size_t)grow * 1024 + gcol] = acc[i][j][r] + bof;   // fp32 store
      }
    }
}

// ---------------------------------------------------------------------------
extern "C" void kernel_launch(void* const* d_in, const int* in_sizes, int n_in,
                              void* d_out, int out_size, void* d_ws, size_t ws_size,
                              hipStream_t stream) {
  const float* x    = (const float*)d_in[0];
  const float* Wq   = (const float*)d_in[1];
  const float* Wkv  = (const float*)d_in[2];
  const float* Wo   = (const float*)d_in[3];
  const float* bo   = (const float*)d_in[4];
  const float* rel  = (const float*)d_in[5];
  float* out = (float*)d_out;                 // fp32 output

  char* ws = (char*)d_ws;
  u16*   WoT  = (u16*)(ws + 0);          //  2 MB
  float* btab = (float*)(ws + 2097152);  //  0.25 MB
  u16*   Qb   = (u16*)(ws + 2359296);    //  8 MB
  u16*   Kbuf = (u16*)(ws + 10747904);   //  8 MB
  u16*   VTb  = (u16*)(ws + 19136512);   //  8 MB
  u16*   AO   = (u16*)(ws + 27525120);   //  8 MB
  // Wall (3072x1024 bf16 = 6 MB) aliases AO: consumed by proj_gemm before
  // attn_k writes AO (stream-ordered). Peak workspace = 35.9 MB (< previous).
  u16*   Wall = AO;

  bias_table_k<<<16, 256, 0, stream>>>(rel, btab);
  transpose_cvt_k<<<dim3(32, 32), dim3(32, 8), 0, stream>>>(Wo, WoT, 1024, 0);

  // Build fused weight: rows 0-1023 Q, 1024-2047 K, 2048-3071 V (all [out][in])
  transpose_cvt_k<<<dim3(32, 32), dim3(32, 8), 0, stream>>>(Wq,  Wall,                 1024, 0);
  transpose_cvt_k<<<dim3(32, 32), dim3(32, 8), 0, stream>>>(Wkv, Wall + 1024 * 1024,   2048, 0);
  transpose_cvt_k<<<dim3(32, 32), dim3(32, 8), 0, stream>>>(Wkv, Wall + 2048 * 1024,   2048, 1024);

  proj_gemm_k<<<dim3(32, 24), 256, 0, stream>>>(x, Wall, Qb, Kbuf, VTb);

  attn_k<<<dim3(32, 32), 256, 0, stream>>>(Qb, Kbuf, VTb, btab, AO);
  out_gemm_k<<<dim3(64, 8), 256, 0, stream>>>(AO, WoT, bo, out);
}

// Round 6
// 317.988 us; speedup vs baseline: 1.1197x; 1.0101x over previous
//
#include <hip/hip_runtime.h>

typedef unsigned short u16;
typedef __attribute__((ext_vector_type(8))) __bf16 bf16x8;
typedef __attribute__((ext_vector_type(4))) float f32x4;

#define MFMA16(a, b, c) __builtin_amdgcn_mfma_f32_16x16x32_bf16((a), (b), (c), 0, 0, 0)

__device__ __forceinline__ u16 f2bf(float f) {
  union { float f; unsigned u; } c; c.f = f;
  unsigned u = c.u;
  u += 0x7FFFu + ((u >> 16) & 1u);   // round-to-nearest-even
  return (u16)(u >> 16);
}

__device__ __forceinline__ bf16x8 pack8(const float4& a, const float4& b) {
  union { u16 u[8]; bf16x8 v; } r;
  r.u[0] = f2bf(a.x); r.u[1] = f2bf(a.y); r.u[2] = f2bf(a.z); r.u[3] = f2bf(a.w);
  r.u[4] = f2bf(b.x); r.u[5] = f2bf(b.y); r.u[6] = f2bf(b.z); r.u[7] = f2bf(b.w);
  return r.v;
}

// ---------------------------------------------------------------------------
// Fused weight transpose+cvt: 4 slices in one launch (grid.z selects slice).
// Per-element math identical to the verified transpose_cvt_k.
//   z=0: Wo  (1024x1024, ld 1024, col0    0) -> WoT
//   z=1: Wq  (1024x1024, ld 1024, col0    0) -> Wall + 0
//   z=2: Wkv (1024x2048, ld 2048, col0    0) -> Wall + 1M   (K channels)
//   z=3: Wkv (1024x2048, ld 2048, col0 1024) -> Wall + 2M   (V channels)
// ---------------------------------------------------------------------------
__global__ __launch_bounds__(256) void transpose_all_k(
    const float* __restrict__ Wq, const float* __restrict__ Wkv,
    const float* __restrict__ Wo, u16* __restrict__ Wall,
    u16* __restrict__ WoT) {
  __shared__ u16 t[32][33];
  const int z = blockIdx.z;
  const float* src; u16* dst; int C_ld, col0;
  if (z == 0)      { src = Wo;  dst = WoT;                C_ld = 1024; col0 = 0; }
  else if (z == 1) { src = Wq;  dst = Wall;               C_ld = 1024; col0 = 0; }
  else if (z == 2) { src = Wkv; dst = Wall + 1024 * 1024; C_ld = 2048; col0 = 0; }
  else             { src = Wkv; dst = Wall + 2048 * 1024; C_ld = 2048; col0 = 1024; }
  const int bx = blockIdx.x * 32;
  const int by = blockIdx.y * 32;
  const int tx = threadIdx.x;
  for (int yo = threadIdx.y; yo < 32; yo += 8)
    t[yo][tx] = f2bf(src[(size_t)(by + yo) * C_ld + col0 + bx + tx]);
  __syncthreads();
  for (int yo = threadIdx.y; yo < 32; yo += 8)
    dst[(size_t)(bx + yo) * 1024 + by + tx] = t[tx][yo];
}

// ---------------------------------------------------------------------------
// T5 bias table: tab[delta + 2047][h], delta = j - i. fp32, as-shown semantics.
// ---------------------------------------------------------------------------
__global__ void bias_table_k(const float* __restrict__ rel_emb, float* __restrict__ tab) {
  int idx = blockIdx.x * blockDim.x + threadIdx.x;
  if (idx >= 4095) return;
  int delta = idx - 2047;   // j - i
  int n = -delta;           // i - j
  int ret = 0;
  if (n < 0) { ret = 16; n = -n; }
  int bucket;
  if (n < 8) {
    bucket = n;
  } else {
    int vl = 8 + (int)(2.0f * __log2f((float)n * 0.125f));
    bucket = vl < 15 ? vl : 15;
  }
  bucket += ret;
#pragma unroll
  for (int h = 0; h < 16; h++)
    tab[(size_t)idx * 16 + h] = rel_emb[bucket * 16 + h];
}

// ---------------------------------------------------------------------------
// Fused projection GEMM: Xf(4096x1024 fp32) @ Wall^T (Wall: 3072x1024 bf16
// [out][in]; rows 0-1023 = Q channels, 1024-2047 = K, 2048-3071 = V).
// Grid (32, 24) = 768 blocks. (Verified in R5.)
// ---------------------------------------------------------------------------
__global__ __launch_bounds__(256) void proj_gemm_k(
    const float* __restrict__ Xf, const u16* __restrict__ WT,
    u16* __restrict__ dstQ, u16* __restrict__ dstK, u16* __restrict__ dstVT) {
  __shared__ __align__(16) u16 As[128 * 32];
  __shared__ __align__(16) u16 Bs[128 * 32];
  f32x4 acc[4][4];
#pragma unroll
  for (int i = 0; i < 4; i++)
#pragma unroll
    for (int j = 0; j < 4; j++) acc[i][j] = f32x4{0.f, 0.f, 0.f, 0.f};

  const int m0 = blockIdx.x * 128;
  const int n0 = blockIdx.y * 128;          // 0..2944 over the 3072 fused cols
  const int tid  = threadIdx.x;
  const int lane = tid & 63;
  const int wave = tid >> 6;
  const int wr = (wave >> 1) * 64;
  const int wc = (wave & 1) * 64;
  const int lr = lane & 15;
  const int lk = (lane >> 4) * 8;
  const int r0 = tid >> 2;
  const int sg = (tid & 3) * 8;

  const float* ap0 = Xf + (size_t)(m0 + r0) * 1024 + sg;
  const float* ap1 = Xf + (size_t)(m0 + 64 + r0) * 1024 + sg;
  const u16* bp0 = WT + (size_t)(n0 + r0) * 1024 + sg;
  const u16* bp1 = WT + (size_t)(n0 + 64 + r0) * 1024 + sg;
  u16* as0 = As + r0 * 32 + sg;
  u16* as1 = As + (64 + r0) * 32 + sg;
  u16* bs0 = Bs + r0 * 32 + sg;
  u16* bs1 = Bs + (64 + r0) * 32 + sg;

  for (int k0 = 0; k0 < 1024; k0 += 32) {
    __syncthreads();
    float4 a00 = *(const float4*)(ap0 + k0);
    float4 a01 = *(const float4*)(ap0 + k0 + 4);
    float4 a10 = *(const float4*)(ap1 + k0);
    float4 a11 = *(const float4*)(ap1 + k0 + 4);
    bf16x8 vb0 = *(const bf16x8*)(bp0 + k0);
    bf16x8 vb1 = *(const bf16x8*)(bp1 + k0);
    *(bf16x8*)as0 = pack8(a00, a01);
    *(bf16x8*)as1 = pack8(a10, a11);
    *(bf16x8*)bs0 = vb0;
    *(bf16x8*)bs1 = vb1;
    __syncthreads();
    bf16x8 af[4], bfv[4];
#pragma unroll
    for (int i = 0; i < 4; i++)
      af[i] = *(const bf16x8*)(As + (wr + i * 16 + lr) * 32 + lk);
#pragma unroll
    for (int j = 0; j < 4; j++)
      bfv[j] = *(const bf16x8*)(Bs + (wc + j * 16 + lr) * 32 + lk);
#pragma unroll
    for (int i = 0; i < 4; i++)
#pragma unroll
      for (int j = 0; j < 4; j++)
        acc[i][j] = MFMA16(af[i], bfv[j], acc[i][j]);
  }

  const int orow = (lane >> 4) * 4, ocol = lane & 15;
#pragma unroll
  for (int i = 0; i < 4; i++)
#pragma unroll
    for (int j = 0; j < 4; j++)
#pragma unroll
      for (int r = 0; r < 4; r++) {
        int grow = m0 + wr + i * 16 + orow + r;   // token
        int gcol = n0 + wc + j * 16 + ocol;       // fused channel 0..3071
        int b = grow >> 11, n = grow & 2047;
        int seg = gcol >> 10;                     // 0=Q, 1=K, 2=V (uniform/block)
        int c = gcol & 1023;
        int h = c >> 6, d = c & 63;
        u16 bv = f2bf(acc[i][j][r]);
        if (seg == 0)
          dstQ[(((size_t)b * 16 + h) * 2048 + n) * 64 + d] = bv;
        else if (seg == 1)
          dstK[(((size_t)b * 16 + h) * 2048 + n) * 64 + d] = bv;
        else
          dstVT[(((size_t)b * 16 + h) * 64 + d) * 2048 + n] = bv;
      }
}

// ---------------------------------------------------------------------------
// Flash attention with T5 bias. Block = 64 Q-rows of one (b,h); K-chunks of 64.
// R6 change (scheduling only, values bit-identical to verified version):
// T14 async-STAGE split — tile t+1's global loads issue into registers at the
// top of iteration t (latency hides under QK/softmax/PV), and the LDS writes
// happen after the post-PV barrier. Barrier count per iteration unchanged (3).
// ---------------------------------------------------------------------------
__global__ __launch_bounds__(256) void attn_k(
    const u16* __restrict__ Q, const u16* __restrict__ Kb,
    const u16* __restrict__ VT, const float* __restrict__ bias_tab,
    u16* __restrict__ AO) {
  const int tid = threadIdx.x;
  const int lane = tid & 63, wave = tid >> 6;
  const int lr = lane & 15, lq = lane >> 4, lk = lq * 8;
  const int bh = blockIdx.y, b = bh >> 4, h = bh & 15;
  const int q0 = blockIdx.x * 64;

  __shared__ __align__(16) u16 Qs[64 * 72];
  __shared__ __align__(16) u16 Ks[64 * 72];
  __shared__ __align__(16) u16 Vs[64 * 72];
  __shared__ __align__(16) u16 Ps[64 * 72];
  __shared__ float Bls[128];

  const u16* Qg = Q + ((size_t)bh * 2048 + q0) * 64;
  const u16* Kg = Kb + (size_t)bh * 2048 * 64;
  const u16* Vg = VT + (size_t)bh * 64 * 2048;
  const int ra = tid >> 3, sa = (tid & 7) * 8;

  // --- prologue: stage Q and K/V/Bls tile 0, single barrier ---
  {
    *(bf16x8*)(Qs + ra * 72 + sa)        = *(const bf16x8*)(Qg + (size_t)ra * 64 + sa);
    *(bf16x8*)(Qs + (32 + ra) * 72 + sa) = *(const bf16x8*)(Qg + (size_t)(32 + ra) * 64 + sa);
    *(bf16x8*)(Ks + ra * 72 + sa)        = *(const bf16x8*)(Kg + (size_t)ra * 64 + sa);
    *(bf16x8*)(Ks + (32 + ra) * 72 + sa) = *(const bf16x8*)(Kg + (size_t)(32 + ra) * 64 + sa);
    *(bf16x8*)(Vs + ra * 72 + sa)        = *(const bf16x8*)(Vg + (size_t)ra * 2048 + sa);
    *(bf16x8*)(Vs + (32 + ra) * 72 + sa) = *(const bf16x8*)(Vg + (size_t)(32 + ra) * 2048 + sa);
    if (tid < 127) Bls[tid] = bias_tab[(size_t)(0 - q0 + tid - 63 + 2047) * 16 + h];
  }
  __syncthreads();
  bf16x8 qf0 = *(const bf16x8*)(Qs + (wave * 16 + lr) * 72 + lk);
  bf16x8 qf1 = *(const bf16x8*)(Qs + (wave * 16 + lr) * 72 + 32 + lk);

  float m_run[4], l_run[4];
  f32x4 o[4];
#pragma unroll
  for (int r = 0; r < 4; r++) { m_run[r] = -1.0e30f; l_run[r] = 0.f; }
#pragma unroll
  for (int dt = 0; dt < 4; dt++) o[dt] = f32x4{0.f, 0.f, 0.f, 0.f};

  const int i_base = wave * 16 + lq * 4;
  const float scale = 0.125f;

  for (int kc = 0; kc < 2048; kc += 64) {
    // --- issue tile t+1 global loads into regs (no wait; uniform predicate) ---
    const int kcn = kc + 64;
    const bool have_next = (kcn < 2048);
    bf16x8 nk0, nk1, nv0, nv1;
    float nbls = 0.f;
    if (have_next) {
      nk0 = *(const bf16x8*)(Kg + (size_t)(kcn + ra) * 64 + sa);
      nk1 = *(const bf16x8*)(Kg + (size_t)(kcn + 32 + ra) * 64 + sa);
      nv0 = *(const bf16x8*)(Vg + (size_t)ra * 2048 + kcn + sa);
      nv1 = *(const bf16x8*)(Vg + (size_t)(32 + ra) * 2048 + kcn + sa);
      if (tid < 127) nbls = bias_tab[(size_t)(kcn - q0 + tid - 63 + 2047) * 16 + h];
    }

    // --- compute on tile t (LDS already holds it) ---
    f32x4 sc[4];
#pragma unroll
    for (int jt = 0; jt < 4; jt++) {
      bf16x8 kb0 = *(const bf16x8*)(Ks + (jt * 16 + lr) * 72 + lk);
      bf16x8 kb1 = *(const bf16x8*)(Ks + (jt * 16 + lr) * 72 + 32 + lk);
      f32x4 z = {0.f, 0.f, 0.f, 0.f};
      z = MFMA16(qf0, kb0, z);
      z = MFMA16(qf1, kb1, z);
      sc[jt] = z;
    }

    float mc[4] = {-1.0e30f, -1.0e30f, -1.0e30f, -1.0e30f};
#pragma unroll
    for (int jt = 0; jt < 4; jt++) {
      int base = jt * 16 + lr - i_base + 63;
#pragma unroll
      for (int r = 0; r < 4; r++) {
        float sv = sc[jt][r] * scale + Bls[base - r];
        sc[jt][r] = sv;
        mc[r] = fmaxf(mc[r], sv);
      }
    }
#pragma unroll
    for (int m = 1; m < 16; m <<= 1)
#pragma unroll
      for (int r = 0; r < 4; r++)
        mc[r] = fmaxf(mc[r], __shfl_xor(mc[r], m));

    float alpha[4], ls[4];
#pragma unroll
    for (int r = 0; r < 4; r++) {
      float mn = fmaxf(m_run[r], mc[r]);
      alpha[r] = __expf(m_run[r] - mn);
      m_run[r] = mn;
      ls[r] = 0.f;
    }
#pragma unroll
    for (int jt = 0; jt < 4; jt++)
#pragma unroll
      for (int r = 0; r < 4; r++) {
        float p = __expf(sc[jt][r] - m_run[r]);
        sc[jt][r] = p;
        ls[r] += p;
      }
#pragma unroll
    for (int m = 1; m < 16; m <<= 1)
#pragma unroll
      for (int r = 0; r < 4; r++)
        ls[r] += __shfl_xor(ls[r], m);
#pragma unroll
    for (int r = 0; r < 4; r++)
      l_run[r] = l_run[r] * alpha[r] + ls[r];
#pragma unroll
    for (int dt = 0; dt < 4; dt++)
#pragma unroll
      for (int r = 0; r < 4; r++)
        o[dt][r] *= alpha[r];

#pragma unroll
    for (int jt = 0; jt < 4; jt++)
#pragma unroll
      for (int r = 0; r < 4; r++)
        Ps[(wave * 16 + lq * 4 + r) * 72 + jt * 16 + lr] = f2bf(sc[jt][r]);
    __syncthreads();   // Ps visible (all Ks/Bls reads also complete)

    bf16x8 p0 = *(const bf16x8*)(Ps + (wave * 16 + lr) * 72 + lk);
    bf16x8 p1 = *(const bf16x8*)(Ps + (wave * 16 + lr) * 72 + 32 + lk);
#pragma unroll
    for (int dt = 0; dt < 4; dt++) {
      bf16x8 v0 = *(const bf16x8*)(Vs + (dt * 16 + lr) * 72 + lk);
      bf16x8 v1 = *(const bf16x8*)(Vs + (dt * 16 + lr) * 72 + 32 + lk);
      o[dt] = MFMA16(p0, v0, o[dt]);
      o[dt] = MFMA16(p1, v1, o[dt]);
    }
    __syncthreads();   // all Vs/Ps reads complete; safe to overwrite LDS

    // --- write-late stage: tile t+1 regs -> LDS ---
    if (have_next) {
      *(bf16x8*)(Ks + ra * 72 + sa)        = nk0;
      *(bf16x8*)(Ks + (32 + ra) * 72 + sa) = nk1;
      *(bf16x8*)(Vs + ra * 72 + sa)        = nv0;
      *(bf16x8*)(Vs + (32 + ra) * 72 + sa) = nv1;
      if (tid < 127) Bls[tid] = nbls;
    }
    __syncthreads();   // tile t+1 ready
  }

#pragma unroll
  for (int dt = 0; dt < 4; dt++)
#pragma unroll
    for (int r = 0; r < 4; r++) {
      float ov = o[dt][r] / l_run[r];
      int n = q0 + wave * 16 + lq * 4 + r;
      int d = dt * 16 + lr;
      AO[((size_t)b * 2048 + n) * 1024 + h * 64 + d] = f2bf(ov);
    }
}

// ---------------------------------------------------------------------------
// Output GEMM: AO(4096x1024 bf16) @ WoT^T + bo -> out (fp32).
// 64x128 tiles, grid (64, 8) = 512 blocks. (Verified in R5.)
// ---------------------------------------------------------------------------
__global__ __launch_bounds__(256) void out_gemm_k(
    const u16* __restrict__ AO, const u16* __restrict__ WoT,
    const float* __restrict__ bo, float* __restrict__ out) {
  __shared__ __align__(16) u16 As[64 * 32];
  __shared__ __align__(16) u16 Bs[128 * 32];
  f32x4 acc[4][2];
#pragma unroll
  for (int i = 0; i < 4; i++)
#pragma unroll
    for (int j = 0; j < 2; j++) acc[i][j] = f32x4{0.f, 0.f, 0.f, 0.f};

  const int m0 = blockIdx.x * 64;
  const int n0 = blockIdx.y * 128;
  const int tid  = threadIdx.x;
  const int lane = tid & 63;
  const int wave = tid >> 6;
  const int wc = wave * 32;            // each wave: 64 rows x 32 cols
  const int lr = lane & 15;
  const int lk = (lane >> 4) * 8;
  const int r0 = tid >> 2;
  const int sg = (tid & 3) * 8;

  const u16* ap  = AO + (size_t)(m0 + r0) * 1024 + sg;
  const u16* bp0 = WoT + (size_t)(n0 + r0) * 1024 + sg;
  const u16* bp1 = WoT + (size_t)(n0 + 64 + r0) * 1024 + sg;
  u16* as  = As + r0 * 32 + sg;
  u16* bs0 = Bs + r0 * 32 + sg;
  u16* bs1 = Bs + (64 + r0) * 32 + sg;

  for (int k0 = 0; k0 < 1024; k0 += 32) {
    __syncthreads();
    bf16x8 va  = *(const bf16x8*)(ap + k0);
    bf16x8 vb0 = *(const bf16x8*)(bp0 + k0);
    bf16x8 vb1 = *(const bf16x8*)(bp1 + k0);
    *(bf16x8*)as  = va;
    *(bf16x8*)bs0 = vb0;
    *(bf16x8*)bs1 = vb1;
    __syncthreads();
    bf16x8 af[4], bfv[2];
#pragma unroll
    for (int i = 0; i < 4; i++)
      af[i] = *(const bf16x8*)(As + (i * 16 + lr) * 32 + lk);
#pragma unroll
    for (int j = 0; j < 2; j++)
      bfv[j] = *(const bf16x8*)(Bs + (wc + j * 16 + lr) * 32 + lk);
#pragma unroll
    for (int i = 0; i < 4; i++)
#pragma unroll
      for (int j = 0; j < 2; j++)
        acc[i][j] = MFMA16(af[i], bfv[j], acc[i][j]);
  }

  const int orow = (lane >> 4) * 4, ocol = lane & 15;
#pragma unroll
  for (int i = 0; i < 4; i++)
#pragma unroll
    for (int j = 0; j < 2; j++) {
      int gcol = n0 + wc + j * 16 + ocol;
      float bof = bo[gcol];
#pragma unroll
      for (int r = 0; r < 4; r++) {
        int grow = m0 + i * 16 + orow + r;
        out[(size_t)grow * 1024 + gcol] = acc[i][j][r] + bof;   // fp32 store
      }
    }
}

// ---------------------------------------------------------------------------
extern "C" void kernel_launch(void* const* d_in, const int* in_sizes, int n_in,
                              void* d_out, int out_size, void* d_ws, size_t ws_size,
                              hipStream_t stream) {
  const float* x    = (const float*)d_in[0];
  const float* Wq   = (const float*)d_in[1];
  const float* Wkv  = (const float*)d_in[2];
  const float* Wo   = (const float*)d_in[3];
  const float* bo   = (const float*)d_in[4];
  const float* rel  = (const float*)d_in[5];
  float* out = (float*)d_out;                 // fp32 output

  char* ws = (char*)d_ws;
  u16*   WoT  = (u16*)(ws + 0);          //  2 MB
  float* btab = (float*)(ws + 2097152);  //  0.25 MB
  u16*   Qb   = (u16*)(ws + 2359296);    //  8 MB
  u16*   Kbuf = (u16*)(ws + 10747904);   //  8 MB
  u16*   VTb  = (u16*)(ws + 19136512);   //  8 MB
  u16*   AO   = (u16*)(ws + 27525120);   //  8 MB
  // Wall (3072x1024 bf16 = 6 MB) aliases AO: consumed by proj_gemm before
  // attn_k writes AO (stream-ordered).
  u16*   Wall = AO;

  bias_table_k<<<16, 256, 0, stream>>>(rel, btab);
  // All 4 weight transposes in one launch (z: Wo, Wq, Wkv-K, Wkv-V)
  transpose_all_k<<<dim3(32, 32, 4), dim3(32, 8), 0, stream>>>(Wq, Wkv, Wo, Wall, WoT);

  proj_gemm_k<<<dim3(32, 24), 256, 0, stream>>>(x, Wall, Qb, Kbuf, VTb);

  attn_k<<<dim3(32, 32), 256, 0, stream>>>(Qb, Kbuf, VTb, btab, AO);
  out_gemm_k<<<dim3(64, 8), 256, 0, stream>>>(AO, WoT, bo, out);
}

// Round 7
// 300.906 us; speedup vs baseline: 1.1833x; 1.0568x over previous
//
#include <hip/hip_runtime.h>

typedef unsigned short u16;
typedef __attribute__((ext_vector_type(8))) __bf16 bf16x8;
typedef __attribute__((ext_vector_type(4))) float f32x4;

#define MFMA16(a, b, c) __builtin_amdgcn_mfma_f32_16x16x32_bf16((a), (b), (c), 0, 0, 0)

__device__ __forceinline__ u16 f2bf(float f) {
  union { float f; unsigned u; } c; c.f = f;
  unsigned u = c.u;
  u += 0x7FFFu + ((u >> 16) & 1u);   // round-to-nearest-even
  return (u16)(u >> 16);
}

__device__ __forceinline__ bf16x8 pack8(const float4& a, const float4& b) {
  union { u16 u[8]; bf16x8 v; } r;
  r.u[0] = f2bf(a.x); r.u[1] = f2bf(a.y); r.u[2] = f2bf(a.z); r.u[3] = f2bf(a.w);
  r.u[4] = f2bf(b.x); r.u[5] = f2bf(b.y); r.u[6] = f2bf(b.z); r.u[7] = f2bf(b.w);
  return r.v;
}

// async global->LDS, 16 bytes/lane. LDS dest must be base + lane*16 in wave
// lane order (m104 constraint) — all call sites below satisfy byte = tid*16.
__device__ __forceinline__ void async_cp16(u16* l, const u16* g) {
  __builtin_amdgcn_global_load_lds(
      (const __attribute__((address_space(1))) unsigned int*)g,
      (__attribute__((address_space(3))) unsigned int*)l, 16, 0, 0);
}

// ---------------------------------------------------------------------------
// Fused weight transpose+cvt: 4 slices in one launch (grid.z selects slice).
// ---------------------------------------------------------------------------
__global__ __launch_bounds__(256) void transpose_all_k(
    const float* __restrict__ Wq, const float* __restrict__ Wkv,
    const float* __restrict__ Wo, u16* __restrict__ Wall,
    u16* __restrict__ WoT) {
  __shared__ u16 t[32][33];
  const int z = blockIdx.z;
  const float* src; u16* dst; int C_ld, col0;
  if (z == 0)      { src = Wo;  dst = WoT;                C_ld = 1024; col0 = 0; }
  else if (z == 1) { src = Wq;  dst = Wall;               C_ld = 1024; col0 = 0; }
  else if (z == 2) { src = Wkv; dst = Wall + 1024 * 1024; C_ld = 2048; col0 = 0; }
  else             { src = Wkv; dst = Wall + 2048 * 1024; C_ld = 2048; col0 = 1024; }
  const int bx = blockIdx.x * 32;
  const int by = blockIdx.y * 32;
  const int tx = threadIdx.x;
  for (int yo = threadIdx.y; yo < 32; yo += 8)
    t[yo][tx] = f2bf(src[(size_t)(by + yo) * C_ld + col0 + bx + tx]);
  __syncthreads();
  for (int yo = threadIdx.y; yo < 32; yo += 8)
    dst[(size_t)(bx + yo) * 1024 + by + tx] = t[tx][yo];
}

// ---------------------------------------------------------------------------
// T5 bias table: tab[delta + 2047][h], delta = j - i. fp32, as-shown semantics.
// ---------------------------------------------------------------------------
__global__ void bias_table_k(const float* __restrict__ rel_emb, float* __restrict__ tab) {
  int idx = blockIdx.x * blockDim.x + threadIdx.x;
  if (idx >= 4095) return;
  int delta = idx - 2047;   // j - i
  int n = -delta;           // i - j
  int ret = 0;
  if (n < 0) { ret = 16; n = -n; }
  int bucket;
  if (n < 8) {
    bucket = n;
  } else {
    int vl = 8 + (int)(2.0f * __log2f((float)n * 0.125f));
    bucket = vl < 15 ? vl : 15;
  }
  bucket += ret;
#pragma unroll
  for (int h = 0; h < 16; h++)
    tab[(size_t)idx * 16 + h] = rel_emb[bucket * 16 + h];
}

// ---------------------------------------------------------------------------
// Fused projection GEMM: Xf(4096x1024 fp32) @ Wall^T (3072x1024 bf16 [out][in]).
// R7: B staged via global_load_lds (async, no reg round-trip); A unchanged
// (fp32 -> bf16 cvt requires the register path). Values bit-identical.
// ---------------------------------------------------------------------------
__global__ __launch_bounds__(256) void proj_gemm_k(
    const float* __restrict__ Xf, const u16* __restrict__ WT,
    u16* __restrict__ dstQ, u16* __restrict__ dstK, u16* __restrict__ dstVT) {
  __shared__ __align__(16) u16 As[128 * 32];
  __shared__ __align__(16) u16 Bs[128 * 32];
  f32x4 acc[4][4];
#pragma unroll
  for (int i = 0; i < 4; i++)
#pragma unroll
    for (int j = 0; j < 4; j++) acc[i][j] = f32x4{0.f, 0.f, 0.f, 0.f};

  const int m0 = blockIdx.x * 128;
  const int n0 = blockIdx.y * 128;          // 0..2944 over the 3072 fused cols
  const int tid  = threadIdx.x;
  const int lane = tid & 63;
  const int wave = tid >> 6;
  const int wr = (wave >> 1) * 64;
  const int wc = (wave & 1) * 64;
  const int lr = lane & 15;
  const int lk = (lane >> 4) * 8;
  const int r0 = tid >> 2;
  const int sg = (tid & 3) * 8;

  const float* ap0 = Xf + (size_t)(m0 + r0) * 1024 + sg;
  const float* ap1 = Xf + (size_t)(m0 + 64 + r0) * 1024 + sg;
  const u16* bp0 = WT + (size_t)(n0 + r0) * 1024 + sg;
  const u16* bp1 = WT + (size_t)(n0 + 64 + r0) * 1024 + sg;
  u16* as0 = As + r0 * 32 + sg;            // byte off = tid*16
  u16* as1 = As + (64 + r0) * 32 + sg;
  u16* bs0 = Bs + r0 * 32 + sg;            // byte off = tid*16  (gload_lds ok)
  u16* bs1 = Bs + (64 + r0) * 32 + sg;     // byte off = 4096 + tid*16

  for (int k0 = 0; k0 < 1024; k0 += 32) {
    __syncthreads();
    async_cp16(bs0, bp0 + k0);             // async B stage (2 x 16B/lane)
    async_cp16(bs1, bp1 + k0);
    float4 a00 = *(const float4*)(ap0 + k0);
    float4 a01 = *(const float4*)(ap0 + k0 + 4);
    float4 a10 = *(const float4*)(ap1 + k0);
    float4 a11 = *(const float4*)(ap1 + k0 + 4);
    *(bf16x8*)as0 = pack8(a00, a01);
    *(bf16x8*)as1 = pack8(a10, a11);
    __syncthreads();                        // vmcnt(0)+lgkmcnt(0) drain
    bf16x8 af[4], bfv[4];
#pragma unroll
    for (int i = 0; i < 4; i++)
      af[i] = *(const bf16x8*)(As + (wr + i * 16 + lr) * 32 + lk);
#pragma unroll
    for (int j = 0; j < 4; j++)
      bfv[j] = *(const bf16x8*)(Bs + (wc + j * 16 + lr) * 32 + lk);
#pragma unroll
    for (int i = 0; i < 4; i++)
#pragma unroll
      for (int j = 0; j < 4; j++)
        acc[i][j] = MFMA16(af[i], bfv[j], acc[i][j]);
  }

  const int orow = (lane >> 4) * 4, ocol = lane & 15;
#pragma unroll
  for (int i = 0; i < 4; i++)
#pragma unroll
    for (int j = 0; j < 4; j++)
#pragma unroll
      for (int r = 0; r < 4; r++) {
        int grow = m0 + wr + i * 16 + orow + r;   // token
        int gcol = n0 + wc + j * 16 + ocol;       // fused channel 0..3071
        int b = grow >> 11, n = grow & 2047;
        int seg = gcol >> 10;                     // 0=Q, 1=K, 2=V (uniform/block)
        int c = gcol & 1023;
        int h = c >> 6, d = c & 63;
        u16 bv = f2bf(acc[i][j][r]);
        if (seg == 0)
          dstQ[(((size_t)b * 16 + h) * 2048 + n) * 64 + d] = bv;
        else if (seg == 1)
          dstK[(((size_t)b * 16 + h) * 2048 + n) * 64 + d] = bv;
        else
          dstVT[(((size_t)b * 16 + h) * 64 + d) * 2048 + n] = bv;
      }
}

// ---------------------------------------------------------------------------
// Flash attention with T5 bias. Block = 64 Q-rows of one (b,h); K-chunks of 64.
// Loop body = verified R0 version (T14 reverted — it regressed, R6).
// R7 change: Ps aliases Qs (Qs dead after Q-frag read; first Ps write is two
// barriers later). LDS 37376 -> 28160 B => 5 blocks/CU (was 4).
// ---------------------------------------------------------------------------
__global__ __launch_bounds__(256) void attn_k(
    const u16* __restrict__ Q, const u16* __restrict__ Kb,
    const u16* __restrict__ VT, const float* __restrict__ bias_tab,
    u16* __restrict__ AO) {
  const int tid = threadIdx.x;
  const int lane = tid & 63, wave = tid >> 6;
  const int lr = lane & 15, lq = lane >> 4, lk = lq * 8;
  const int bh = blockIdx.y, b = bh >> 4, h = bh & 15;
  const int q0 = blockIdx.x * 64;

  __shared__ __align__(16) u16 Qs[64 * 72];   // reused as Ps after Q-frag read
  __shared__ __align__(16) u16 Ks[64 * 72];
  __shared__ __align__(16) u16 Vs[64 * 72];
  __shared__ float Bls[128];
  u16* Ps = Qs;

  const u16* Qg = Q + ((size_t)bh * 2048 + q0) * 64;
  {
    int ra = tid >> 3, sa = (tid & 7) * 8;
    *(bf16x8*)(Qs + ra * 72 + sa)        = *(const bf16x8*)(Qg + (size_t)ra * 64 + sa);
    *(bf16x8*)(Qs + (32 + ra) * 72 + sa) = *(const bf16x8*)(Qg + (size_t)(32 + ra) * 64 + sa);
  }
  __syncthreads();
  bf16x8 qf0 = *(const bf16x8*)(Qs + (wave * 16 + lr) * 72 + lk);
  bf16x8 qf1 = *(const bf16x8*)(Qs + (wave * 16 + lr) * 72 + 32 + lk);

  float m_run[4], l_run[4];
  f32x4 o[4];
#pragma unroll
  for (int r = 0; r < 4; r++) { m_run[r] = -1.0e30f; l_run[r] = 0.f; }
#pragma unroll
  for (int dt = 0; dt < 4; dt++) o[dt] = f32x4{0.f, 0.f, 0.f, 0.f};

  const u16* Kg = Kb + (size_t)bh * 2048 * 64;
  const u16* Vg = VT + (size_t)bh * 64 * 2048;
  const int i_base = wave * 16 + lq * 4;
  const float scale = 0.125f;

  for (int kc = 0; kc < 2048; kc += 64) {
    __syncthreads();
    {
      int ra = tid >> 3, sa = (tid & 7) * 8;
      *(bf16x8*)(Ks + ra * 72 + sa)        = *(const bf16x8*)(Kg + (size_t)(kc + ra) * 64 + sa);
      *(bf16x8*)(Ks + (32 + ra) * 72 + sa) = *(const bf16x8*)(Kg + (size_t)(kc + 32 + ra) * 64 + sa);
      *(bf16x8*)(Vs + ra * 72 + sa)        = *(const bf16x8*)(Vg + (size_t)ra * 2048 + kc + sa);
      *(bf16x8*)(Vs + (32 + ra) * 72 + sa) = *(const bf16x8*)(Vg + (size_t)(32 + ra) * 2048 + kc + sa);
      if (tid < 127) Bls[tid] = bias_tab[(size_t)(kc - q0 + tid - 63 + 2047) * 16 + h];
    }
    __syncthreads();

    f32x4 sc[4];
#pragma unroll
    for (int jt = 0; jt < 4; jt++) {
      bf16x8 kb0 = *(const bf16x8*)(Ks + (jt * 16 + lr) * 72 + lk);
      bf16x8 kb1 = *(const bf16x8*)(Ks + (jt * 16 + lr) * 72 + 32 + lk);
      f32x4 z = {0.f, 0.f, 0.f, 0.f};
      z = MFMA16(qf0, kb0, z);
      z = MFMA16(qf1, kb1, z);
      sc[jt] = z;
    }

    float mc[4] = {-1.0e30f, -1.0e30f, -1.0e30f, -1.0e30f};
#pragma unroll
    for (int jt = 0; jt < 4; jt++) {
      int base = jt * 16 + lr - i_base + 63;
#pragma unroll
      for (int r = 0; r < 4; r++) {
        float sv = sc[jt][r] * scale + Bls[base - r];
        sc[jt][r] = sv;
        mc[r] = fmaxf(mc[r], sv);
      }
    }
#pragma unroll
    for (int m = 1; m < 16; m <<= 1)
#pragma unroll
      for (int r = 0; r < 4; r++)
        mc[r] = fmaxf(mc[r], __shfl_xor(mc[r], m));

    float alpha[4], ls[4];
#pragma unroll
    for (int r = 0; r < 4; r++) {
      float mn = fmaxf(m_run[r], mc[r]);
      alpha[r] = __expf(m_run[r] - mn);
      m_run[r] = mn;
      ls[r] = 0.f;
    }
#pragma unroll
    for (int jt = 0; jt < 4; jt++)
#pragma unroll
      for (int r = 0; r < 4; r++) {
        float p = __expf(sc[jt][r] - m_run[r]);
        sc[jt][r] = p;
        ls[r] += p;
      }
#pragma unroll
    for (int m = 1; m < 16; m <<= 1)
#pragma unroll
      for (int r = 0; r < 4; r++)
        ls[r] += __shfl_xor(ls[r], m);
#pragma unroll
    for (int r = 0; r < 4; r++)
      l_run[r] = l_run[r] * alpha[r] + ls[r];
#pragma unroll
    for (int dt = 0; dt < 4; dt++)
#pragma unroll
      for (int r = 0; r < 4; r++)
        o[dt][r] *= alpha[r];

#pragma unroll
    for (int jt = 0; jt < 4; jt++)
#pragma unroll
      for (int r = 0; r < 4; r++)
        Ps[(wave * 16 + lq * 4 + r) * 72 + jt * 16 + lr] = f2bf(sc[jt][r]);
    __syncthreads();

    bf16x8 p0 = *(const bf16x8*)(Ps + (wave * 16 + lr) * 72 + lk);
    bf16x8 p1 = *(const bf16x8*)(Ps + (wave * 16 + lr) * 72 + 32 + lk);
#pragma unroll
    for (int dt = 0; dt < 4; dt++) {
      bf16x8 v0 = *(const bf16x8*)(Vs + (dt * 16 + lr) * 72 + lk);
      bf16x8 v1 = *(const bf16x8*)(Vs + (dt * 16 + lr) * 72 + 32 + lk);
      o[dt] = MFMA16(p0, v0, o[dt]);
      o[dt] = MFMA16(p1, v1, o[dt]);
    }
  }

#pragma unroll
  for (int dt = 0; dt < 4; dt++)
#pragma unroll
    for (int r = 0; r < 4; r++) {
      float ov = o[dt][r] / l_run[r];
      int n = q0 + wave * 16 + lq * 4 + r;
      int d = dt * 16 + lr;
      AO[((size_t)b * 2048 + n) * 1024 + h * 64 + d] = f2bf(ov);
    }
}

// ---------------------------------------------------------------------------
// Output GEMM: AO(4096x1024 bf16) @ WoT^T + bo -> out (fp32).
// 64x128 tiles, grid (64, 8). R7: A and B staged via global_load_lds.
// ---------------------------------------------------------------------------
__global__ __launch_bounds__(256) void out_gemm_k(
    const u16* __restrict__ AO, const u16* __restrict__ WoT,
    const float* __restrict__ bo, float* __restrict__ out) {
  __shared__ __align__(16) u16 As[64 * 32];
  __shared__ __align__(16) u16 Bs[128 * 32];
  f32x4 acc[4][2];
#pragma unroll
  for (int i = 0; i < 4; i++)
#pragma unroll
    for (int j = 0; j < 2; j++) acc[i][j] = f32x4{0.f, 0.f, 0.f, 0.f};

  const int m0 = blockIdx.x * 64;
  const int n0 = blockIdx.y * 128;
  const int tid  = threadIdx.x;
  const int lane = tid & 63;
  const int wave = tid >> 6;
  const int wc = wave * 32;            // each wave: 64 rows x 32 cols
  const int lr = lane & 15;
  const int lk = (lane >> 4) * 8;
  const int r0 = tid >> 2;
  const int sg = (tid & 3) * 8;

  const u16* ap  = AO + (size_t)(m0 + r0) * 1024 + sg;
  const u16* bp0 = WoT + (size_t)(n0 + r0) * 1024 + sg;
  const u16* bp1 = WoT + (size_t)(n0 + 64 + r0) * 1024 + sg;
  u16* as  = As + r0 * 32 + sg;        // byte off = tid*16
  u16* bs0 = Bs + r0 * 32 + sg;        // byte off = tid*16
  u16* bs1 = Bs + (64 + r0) * 32 + sg; // byte off = 4096 + tid*16

  for (int k0 = 0; k0 < 1024; k0 += 32) {
    __syncthreads();
    async_cp16(as,  ap  + k0);
    async_cp16(bs0, bp0 + k0);
    async_cp16(bs1, bp1 + k0);
    __syncthreads();                    // vmcnt(0) drain
    bf16x8 af[4], bfv[2];
#pragma unroll
    for (int i = 0; i < 4; i++)
      af[i] = *(const bf16x8*)(As + (i * 16 + lr) * 32 + lk);
#pragma unroll
    for (int j = 0; j < 2; j++)
      bfv[j] = *(const bf16x8*)(Bs + (wc + j * 16 + lr) * 32 + lk);
#pragma unroll
    for (int i = 0; i < 4; i++)
#pragma unroll
      for (int j = 0; j < 2; j++)
        acc[i][j] = MFMA16(af[i], bfv[j], acc[i][j]);
  }

  const int orow = (lane >> 4) * 4, ocol = lane & 15;
#pragma unroll
  for (int i = 0; i < 4; i++)
#pragma unroll
    for (int j = 0; j < 2; j++) {
      int gcol = n0 + wc + j * 16 + ocol;
      float bof = bo[gcol];
#pragma unroll
      for (int r = 0; r < 4; r++) {
        int grow = m0 + i * 16 + orow + r;
        out[(size_t)grow * 1024 + gcol] = acc[i][j][r] + bof;   // fp32 store
      }
    }
}

// ---------------------------------------------------------------------------
extern "C" void kernel_launch(void* const* d_in, const int* in_sizes, int n_in,
                              void* d_out, int out_size, void* d_ws, size_t ws_size,
                              hipStream_t stream) {
  const float* x    = (const float*)d_in[0];
  const float* Wq   = (const float*)d_in[1];
  const float* Wkv  = (const float*)d_in[2];
  const float* Wo   = (const float*)d_in[3];
  const float* bo   = (const float*)d_in[4];
  const float* rel  = (const float*)d_in[5];
  float* out = (float*)d_out;                 // fp32 output

  char* ws = (char*)d_ws;
  u16*   WoT  = (u16*)(ws + 0);          //  2 MB
  float* btab = (float*)(ws + 2097152);  //  0.25 MB
  u16*   Qb   = (u16*)(ws + 2359296);    //  8 MB
  u16*   Kbuf = (u16*)(ws + 10747904);   //  8 MB
  u16*   VTb  = (u16*)(ws + 19136512);   //  8 MB
  u16*   AO   = (u16*)(ws + 27525120);   //  8 MB
  // Wall (3072x1024 bf16 = 6 MB) aliases AO: consumed by proj_gemm before
  // attn_k writes AO (stream-ordered).
  u16*   Wall = AO;

  bias_table_k<<<16, 256, 0, stream>>>(rel, btab);
  // All 4 weight transposes in one launch (z: Wo, Wq, Wkv-K, Wkv-V)
  transpose_all_k<<<dim3(32, 32, 4), dim3(32, 8), 0, stream>>>(Wq, Wkv, Wo, Wall, WoT);

  proj_gemm_k<<<dim3(32, 24), 256, 0, stream>>>(x, Wall, Qb, Kbuf, VTb);

  attn_k<<<dim3(32, 32), 256, 0, stream>>>(Qb, Kbuf, VTb, btab, AO);
  out_gemm_k<<<dim3(64, 8), 256, 0, stream>>>(AO, WoT, bo, out);
}